// Round 6
// baseline (26.440 us; speedup 1.0000x reference)
//
#include <hip/hip_runtime.h>

namespace {
constexpr int kB = 2, kC = 64, kH = 128, kW = 240;
constexpr int kD0 = 16, kD1 = 5;
constexpr int kWc1 = 285, kWc2 = 242;
constexpr int kPad = 48;              // left pad (>= max disp 45, mult of 4)
constexpr int kRow = 340;             // 48 pad + 240 data + 52 right pad; 16B stride
constexpr int kRowF4 = kRow / 4;      // 85
constexpr int kDataF4 = kW / 4;       // 60
constexpr int kFillF4 = kRowF4 - kDataF4;  // 25 (12 left + 13 right)
constexpr int kThreads = 512;         // 8 waves
constexpr int kCT = 72;               // col-threads per group (4 cols each)
constexpr int kG = 7;                 // channel groups {10,9,9,9,9,9,9}
constexpr int kAcc = kD0 + kD1;       // 21
constexpr int kTStr = 85;             // per-thread partial stride (odd)
constexpr int kSlot = kCT * kTStr;    // 6120 floats per slot
constexpr int kOut1 = kB * kD0 * kH * kWc1;
}

__global__ __launch_bounds__(kThreads, 2)
void anynet_disp_kernel(const float* __restrict__ fr, float* __restrict__ out) {
  __shared__ float E[kC * kRow];   // staged exp(feat_r); write-once, then read-only
  __shared__ float P[2 * kSlot];   // partial slots — DEDICATED, never aliased
  const int blk = blockIdx.x;      // 0..255 : one (b,h) row per block
  const int b = blk >> 7, h = blk & 127;
  const int tid = threadIdx.x;

  // ---- phase A0: pad fills = 1.0 (= exp(0), "invalid disparity")
  for (int i = tid; i < kC * kFillF4; i += kThreads) {
    const int row = i / kFillF4, q = i % kFillF4;
    const int j4 = (q < 12) ? q : q + 60;   // f4 [0,12) and [72,85)
    const float4 one = {1.f, 1.f, 1.f, 1.f};
    *reinterpret_cast<float4*>(&E[row * kRow + 4 * j4]) = one;
  }
  // ---- phase A1: stage exp(feat_r[b,:,h,:])
  const float* fr_bh = fr + (size_t)b * kC * kH * kW + (size_t)h * kW;
  for (int base = tid; base < kC * kDataF4; base += 4 * kThreads) {
    float4 v[4]; int dsti[4];
    #pragma unroll
    for (int u = 0; u < 4; ++u) {
      const int i = base + u * kThreads;
      if (i < kC * kDataF4) {
        const int row = i / kDataF4, xq = i % kDataF4;
        v[u] = *reinterpret_cast<const float4*>(fr_bh + (size_t)row * (kH * kW) + 4 * xq);
        dsti[u] = row * kRow + kPad + 4 * xq;
      } else dsti[u] = -1;
    }
    #pragma unroll
    for (int u = 0; u < 4; ++u) {
      if (dsti[u] >= 0) {
        float4 e;
        e.x = __expf(v[u].x); e.y = __expf(v[u].y);
        e.z = __expf(v[u].z); e.w = __expf(v[u].w);
        *reinterpret_cast<float4*>(&E[dsti[u]]) = e;
      }
    }
  }
  __syncthreads();

  // ---- phase B: thread t owns cols 4t..4t+3; group g owns a channel slice.
  // 14 aligned ds_read_b128 fetch the 56-float window covering all 104 taps.
  const int g = tid / kCT;           // 0..6 active, 7 idle (tid >= 504)
  const int t = tid % kCT;
  float acc[4][kAcc] = {};
  if (g < kG) {
    const int cbeg = (g == 0) ? 0 : 10 + 9 * (g - 1);
    const int clen = (g == 0) ? 10 : 9;
    for (int cc = 0; cc < clen; ++cc) {
      const float* rp = &E[(cbeg + cc) * kRow + 4 * t];
      float w[56];
      #pragma unroll
      for (int q4 = 0; q4 < 14; ++q4) {
        const float4 x = *reinterpret_cast<const float4*>(rp + 4 * q4);
        w[4*q4] = x.x; w[4*q4+1] = x.y; w[4*q4+2] = x.z; w[4*q4+3] = x.w;
      }
      // D0 denominators: s(i) = sum_k w[48+i-3k]; col 3 slides from col 0
      float s[4];
      #pragma unroll
      for (int i = 0; i < 3; ++i) {
        const float a0 = (w[48+i] + w[45+i]) + (w[42+i] + w[39+i]);
        const float a1 = (w[36+i] + w[33+i]) + (w[30+i] + w[27+i]);
        const float a2 = (w[24+i] + w[21+i]) + (w[18+i] + w[15+i]);
        const float a3 = (w[12+i] + w[9+i])  + (w[6+i]  + w[3+i]);
        s[i] = (a0 + a1) + (a2 + a3);
      }
      s[3] = s[0] + w[51] - w[3];
      // D1 denominators: sliding 5-tap sums
      float s2[4];
      s2[0] = ((w[46] + w[47]) + (w[48] + w[49])) + w[50];
      s2[1] = s2[0] + w[51] - w[46];
      s2[2] = s2[1] + w[52] - w[47];
      s2[3] = s2[2] + w[53] - w[48];
      #pragma unroll
      for (int i = 0; i < 4; ++i) {
        const float r = __builtin_amdgcn_rcpf(s[i]);
        #pragma unroll
        for (int k = 0; k < kD0; ++k)
          acc[i][k] = fmaf(w[48 + i - 3 * k], r, acc[i][k]);
        const float r2 = __builtin_amdgcn_rcpf(s2[i]);
        #pragma unroll
        for (int j = 0; j < kD1; ++j)
          acc[i][kD0 + j] = fmaf(w[50 + i - j], r2, acc[i][kD0 + j]);
      }
    }
  }
  __threadfence_block();
  __syncthreads();

  // ---- combine: 2 dedicated slots, 4 barrier-separated rounds, no aliasing.
  // slot0 accumulates g5,g3,g1,g0 ; slot1 accumulates g6,g4,g2.
  if (g == 5 || g == 6) {
    float* R = &P[(g - 5) * kSlot + t * kTStr];
    #pragma unroll
    for (int i = 0; i < 4; ++i)
      #pragma unroll
      for (int k = 0; k < kAcc; ++k) R[i * kAcc + k] = acc[i][k];
  }
  __threadfence_block();
  __syncthreads();
  if (g == 3 || g == 4) {
    float* R = &P[(g - 3) * kSlot + t * kTStr];
    #pragma unroll
    for (int i = 0; i < 4; ++i)
      #pragma unroll
      for (int k = 0; k < kAcc; ++k) R[i * kAcc + k] += acc[i][k];
  }
  __threadfence_block();
  __syncthreads();
  if (g == 1 || g == 2) {
    float* R = &P[(g - 1) * kSlot + t * kTStr];
    #pragma unroll
    for (int i = 0; i < 4; ++i)
      #pragma unroll
      for (int k = 0; k < kAcc; ++k) R[i * kAcc + k] += acc[i][k];
  }
  __threadfence_block();
  __syncthreads();
  if (g == 0) {
    float* R = &P[t * kTStr];
    #pragma unroll
    for (int i = 0; i < 4; ++i)
      #pragma unroll
      for (int k = 0; k < kAcc; ++k) R[i * kAcc + k] += acc[i][k];
  }
  __threadfence_block();
  __syncthreads();

  // ---- final: sum the 2 slots, coalesced writes
  for (int i = tid; i < kD0 * kWc1; i += kThreads) {
    const int d = i / kWc1, col = i % kWc1;
    const int o = (col >> 2) * kTStr + (col & 3) * kAcc + d;
    const float vsum = P[o] + P[kSlot + o];
    out[((b * kD0 + d) * kH + h) * kWc1 + col] =
        (3.0f * (float)d) * (4.0f + vsum);            // C/D0 = 4
  }
  for (int i = tid; i < kD1 * kWc2; i += kThreads) {
    const int j = i / kWc2, col = i % kWc2;
    const int o = (col >> 2) * kTStr + (col & 3) * kAcc + kD0 + j;
    const float vsum = P[o] + P[kSlot + o];
    out[kOut1 + ((b * kD1 + j) * kH + h) * kWc2 + col] =
        (float)(j - 2) * (64.0f / 5.0f + vsum);       // C/D1 = 12.8
  }
}

extern "C" void kernel_launch(void* const* d_in, const int* in_sizes, int n_in,
                              void* d_out, int out_size, void* d_ws, size_t ws_size,
                              hipStream_t stream) {
  const float* feat_r = (const float*)d_in[1];  // feats_l contributes exactly C/D
  float* out = (float*)d_out;
  anynet_disp_kernel<<<dim3(kB * kH), dim3(kThreads), 0, stream>>>(feat_r, out);
}

// Round 7
// 18.906 us; speedup vs baseline: 1.3985x; 1.3985x over previous
//
#include <hip/hip_runtime.h>

namespace {
constexpr int kB   = 2;
constexpr int kC   = 64;
constexpr int kH   = 128;
constexpr int kW   = 240;
constexpr int kD0  = 16;          // disps 0,3,...,45
constexpr int kD1  = 5;           // disps -2,-1,0,1,2
constexpr int kWc1 = 285;
constexpr int kWc2 = 242;
constexpr int kPad = 48;          // left pad (>= max disp 45)
constexpr int kRow = 336;         // padded row stride (floats)
constexpr int kGroups   = 3;      // channel-parallel groups (R2 geometry)
constexpr int kGThreads = 320;    // 5 waves per group -> wave-aligned
constexpr int kThreads  = kGroups * kGThreads;  // 960 = 15 waves
constexpr int kAcc  = kD0 + kD1;  // 21
constexpr int kRStr = kWc1 * kAcc;             // 5985 floats per partial slot
constexpr int kOut1 = kB * kD0 * kH * kWc1;
constexpr int kN1   = kD0 * kWc1;              // 4560
constexpr int kN2   = kD1 * kWc2;              // 1210
typedef float v2f __attribute__((ext_vector_type(2)));
}

__global__ __launch_bounds__(kThreads, 4)
void anynet_disp_kernel(const float* __restrict__ fr, float* __restrict__ out) {
  __shared__ float E[kC * kRow];      // staged exp(feat_r), write-once then RO
  __shared__ float P[kGroups * kRStr];// dedicated partial slots (no aliasing)
  const int bh  = blockIdx.x;         // 0..255
  const int b   = bh >> 7;
  const int h   = bh & 127;
  const int tid = threadIdx.x;

  // ---- phase A0: pads = 1.0 (= exp(0), the "invalid disparity" value)
  for (int i = tid; i < kC * 96; i += kThreads) {
    const int row = i / 96;
    const int off = i % 96;
    const int j   = (off < kPad) ? off : off + kW;  // [0,48) and [288,336)
    E[row * kRow + j] = 1.0f;
  }
  // ---- phase A1: stage exp(feat_r[b,:,h,:]) as float4 (R2-validated)
  for (int i = tid; i < kC * (kW / 4); i += kThreads) {
    const int row = i / 60;
    const int xq  = i % 60;
    const float4 v =
        reinterpret_cast<const float4*>(fr)[(((b * kC + row) * kH + h) * kW) / 4 + xq];
    float4 e;
    e.x = __expf(v.x); e.y = __expf(v.y); e.z = __expf(v.z); e.w = __expf(v.w);
    reinterpret_cast<float4*>(&E[row * kRow + kPad])[xq] = e;
  }
  __syncthreads();

  // ---- phase B: group g = channel slice {22,21,21}; thread col t.
  // 10 ds_read2_b32 fetch all 20 distinct taps (base = padded idx t+3):
  //   D0 tap k at dword offset 45-3k ; D1 extras at 43,44,46,47.
  const int g = tid / kGThreads;      // 0..2
  const int t = tid % kGThreads;
  float acc1[kD0] = {};
  float acc2[kD1] = {};
  if (t < kWc1) {
    const int cbeg = (g == 0) ? 0 : 22 + (g - 1) * 21;
    const int clen = (g == 0) ? 22 : 21;
    uint32_t addr = (uint32_t)(uintptr_t)(const void*)&E[cbeg * kRow + t + 3];
    for (int cc = 0; cc < clen; ++cc) {
      v2f p0, p1, p2, p3, p4, p5, p6, p7, q0, q1;
      asm volatile(
          "ds_read2_b32 %0, %10 offset0:45 offset1:42\n\t"
          "ds_read2_b32 %1, %10 offset0:39 offset1:36\n\t"
          "ds_read2_b32 %2, %10 offset0:33 offset1:30\n\t"
          "ds_read2_b32 %3, %10 offset0:27 offset1:24\n\t"
          "ds_read2_b32 %4, %10 offset0:21 offset1:18\n\t"
          "ds_read2_b32 %5, %10 offset0:15 offset1:12\n\t"
          "ds_read2_b32 %6, %10 offset0:9 offset1:6\n\t"
          "ds_read2_b32 %7, %10 offset0:3 offset1:0\n\t"
          "ds_read2_b32 %8, %10 offset0:43 offset1:44\n\t"
          "ds_read2_b32 %9, %10 offset0:46 offset1:47\n\t"
          "s_waitcnt lgkmcnt(0)"
          : "=&v"(p0), "=&v"(p1), "=&v"(p2), "=&v"(p3), "=&v"(p4),
            "=&v"(p5), "=&v"(p6), "=&v"(p7), "=&v"(q0), "=&v"(q1)
          : "v"(addr));
      // D0: tap[2i] = p_i.x, tap[2i+1] = p_i.y  (tap k = row[t+48-3k])
      const float a0 = (p0.x + p0.y) + (p1.x + p1.y);
      const float a1 = (p2.x + p2.y) + (p3.x + p3.y);
      const float a2 = (p4.x + p4.y) + (p5.x + p5.y);
      const float a3 = (p6.x + p6.y) + (p7.x + p7.y);
      const float s  = (a0 + a1) + (a2 + a3);
      const float r  = __builtin_amdgcn_rcpf(s);
      acc1[0]  = fmaf(p0.x, r, acc1[0]);   acc1[1]  = fmaf(p0.y, r, acc1[1]);
      acc1[2]  = fmaf(p1.x, r, acc1[2]);   acc1[3]  = fmaf(p1.y, r, acc1[3]);
      acc1[4]  = fmaf(p2.x, r, acc1[4]);   acc1[5]  = fmaf(p2.y, r, acc1[5]);
      acc1[6]  = fmaf(p3.x, r, acc1[6]);   acc1[7]  = fmaf(p3.y, r, acc1[7]);
      acc1[8]  = fmaf(p4.x, r, acc1[8]);   acc1[9]  = fmaf(p4.y, r, acc1[9]);
      acc1[10] = fmaf(p5.x, r, acc1[10]);  acc1[11] = fmaf(p5.y, r, acc1[11]);
      acc1[12] = fmaf(p6.x, r, acc1[12]);  acc1[13] = fmaf(p6.y, r, acc1[13]);
      acc1[14] = fmaf(p7.x, r, acc1[14]);  acc1[15] = fmaf(p7.y, r, acc1[15]);
      // D1: u[j] = row[t+50-j] -> u0=47(q1.y) u1=46(q1.x) u2=45(p0.x)
      //                            u3=44(q0.y) u4=43(q0.x)
      const float s2 = ((q0.x + q0.y) + (q1.x + q1.y)) + p0.x;
      const float r2 = __builtin_amdgcn_rcpf(s2);
      acc2[0] = fmaf(q1.y, r2, acc2[0]);
      acc2[1] = fmaf(q1.x, r2, acc2[1]);
      acc2[2] = fmaf(p0.x, r2, acc2[2]);
      acc2[3] = fmaf(q0.y, r2, acc2[3]);
      acc2[4] = fmaf(q0.x, r2, acc2[4]);
      addr += kRow * 4;
    }
  }
  __syncthreads();

  // ---- phase C: each group writes its OWN slot (disjoint, R2-validated)
  if (t < kWc1) {
    float* __restrict__ R = &P[g * kRStr + t * kAcc];  // stride 21: conflict-free
    #pragma unroll
    for (int k = 0; k < kD0; ++k) R[k] = acc1[k];
    #pragma unroll
    for (int j = 0; j < kD1; ++j) R[kD0 + j] = acc2[j];
  }
  __syncthreads();

  // ---- phase D: combine 3 slots, coalesced writes (R2-validated)
  for (int i = tid; i < kN1 + kN2; i += kThreads) {
    if (i < kN1) {
      const int d   = i / kWc1;
      const int col = i % kWc1;
      const int o   = col * kAcc + d;
      const float v = P[o] + P[kRStr + o] + P[2 * kRStr + o];
      out[((b * kD0 + d) * kH + h) * kWc1 + col] =
          (3.0f * (float)d) * (4.0f + v);              // C/D0 = 4
    } else {
      const int i2  = i - kN1;
      const int j   = i2 / kWc2;
      const int col = i2 % kWc2;
      const int o   = col * kAcc + kD0 + j;
      const float v = P[o] + P[kRStr + o] + P[2 * kRStr + o];
      out[kOut1 + ((b * kD1 + j) * kH + h) * kWc2 + col] =
          (float)(j - 2) * (64.0f / 5.0f + v);         // C/D1 = 12.8
    }
  }
}

extern "C" void kernel_launch(void* const* d_in, const int* in_sizes, int n_in,
                              void* d_out, int out_size, void* d_ws, size_t ws_size,
                              hipStream_t stream) {
  const float* feat_r = (const float*)d_in[1];  // feats_l contributes exactly C/D
  float* out = (float*)d_out;
  anynet_disp_kernel<<<dim3(kB * kH), dim3(kThreads), 0, stream>>>(feat_r, out);
}